// Round 13
// baseline (501.145 us; speedup 1.0000x reference)
//
#include <hip/hip_runtime.h>
#include <hip/hip_bf16.h>
#include <hip/hip_fp16.h>
#include <cstdint>

// Exphormer attention, MI355X.
// K1 convert weights (fp32 -> bf16 hi/lo) + dst histogram ->
// K2 scan1 + scanB (CSR offsets/cursors) ->
// K3 fused QKV projection (bf16 MFMA, weight-split, f16 outputs) ->
// K4 edge kernel, BARRIER-MINIMAL: A-frags read directly from global (L1/L2
//    caches the tile across the block's 4 waves; loads interleave with MFMA
//    in one scheduler region), E-tile in LDS, ONE barrier, CSR-slot score
//    writes + fused scatter ->
// K5 gather: out[dst] = sum score * V[src]; ebuf+scores sequential, V random.

typedef float    f32x4  __attribute__((ext_vector_type(4)));
typedef short    bf16x8 __attribute__((ext_vector_type(8)));
typedef int      i32x4  __attribute__((ext_vector_type(4)));
typedef _Float16 f16x8  __attribute__((ext_vector_type(8)));
typedef _Float16 f16x4  __attribute__((ext_vector_type(4)));

#define AP 136   // A-tile row stride (bf16 elems) in qkv LDS
#define EP 132   // E-tile row stride (f32 elems):  64x132x4 = 33792 B

__device__ __forceinline__ short f2bf(float f) {
    union { float f; uint32_t u; } v; v.f = f;
    uint32_t r = v.u + 0x7FFFu + ((v.u >> 16) & 1u);   // RNE
    return (short)(r >> 16);
}
__device__ __forceinline__ float bf2f(short s) {
    union { uint32_t u; float f; } v; v.u = ((uint32_t)(uint16_t)s) << 16;
    return v.f;
}
__device__ __forceinline__ int cvt2(float a, float b) {
    float2 t; t.x = a; t.y = b;
    __hip_bfloat162 h = __float22bfloat162_rn(t);
    int r; __builtin_memcpy(&r, &h, 4);
    return r;
}
// non-temporal 16B load (streaming data: don't pollute caches)
__device__ __forceinline__ float4 ntload4(const float* p) {
    i32x4 r = __builtin_nontemporal_load((const i32x4*)p);
    float4 f; __builtin_memcpy(&f, &r, 16);
    return f;
}

// ---------------- K1: weight conversion + dst histogram ----------------
// Wall rows: [0:128)=Wq, [128:256)=Wk, [256:384)=Wv, [384:512)=We
__global__ __launch_bounds__(256) void convert_weights(
        const float* __restrict__ Wq, const float* __restrict__ bq,
        const float* __restrict__ Wk, const float* __restrict__ bk,
        const float* __restrict__ We, const float* __restrict__ be,
        const float* __restrict__ Wv, const float* __restrict__ bv,
        const int* __restrict__ dstp, int NE,
        short* __restrict__ Whi, short* __restrict__ Wlo, float* __restrict__ ball,
        int* __restrict__ counts) {
    int idx = blockIdx.x * 256 + threadIdx.x;     // 0..65535
    int wrow = idx >> 7;
    int k = idx & 127;
    int which = wrow >> 7;
    int r = wrow & 127;
    const float* Wsrc = which == 0 ? Wq : which == 1 ? Wk : which == 2 ? Wv : We;
    float f = Wsrc[r * 128 + k];
    short hi = f2bf(f);
    short lo = f2bf(f - bf2f(hi));
    Whi[idx] = hi; Wlo[idx] = lo;
    if (idx < 512) {
        int wh = idx >> 7; int rr = idx & 127;
        const float* bsrc = wh == 0 ? bq : wh == 1 ? bk : wh == 2 ? bv : be;
        ball[idx] = bsrc[rr];
    }
    // fused dst histogram (grid-stride over edges)
    for (int i = idx; i < NE; i += 65536)
        atomicAdd(&counts[dstp[i]], 1);
}

// ---------------- K2: CSR scans ----------------
__global__ __launch_bounds__(1024) void scan1_kernel(const int* __restrict__ counts,
                                                     int* __restrict__ incl,
                                                     int* __restrict__ partials, int n) {
    __shared__ int sh[1024];
    int t = threadIdx.x;
    int i = blockIdx.x * 1024 + t;
    sh[t] = (i < n) ? counts[i] : 0;
    for (int off = 1; off < 1024; off <<= 1) {
        __syncthreads();
        int xv = (t >= off) ? sh[t - off] : 0;
        __syncthreads();
        sh[t] += xv;
    }
    __syncthreads();
    if (i < n) incl[i] = sh[t];
    if (t == 1023) partials[blockIdx.x] = sh[1023];
}

// fused scan2+scan3
__global__ __launch_bounds__(1024) void scanB_kernel(const int* __restrict__ counts,
                                                     int* __restrict__ offsets,
                                                     int* __restrict__ cursors,
                                                     const int* __restrict__ partials,
                                                     int n, int total) {
    int pbase = 0;
    for (int b = 0; b < (int)blockIdx.x; ++b) pbase += partials[b];
    int i = blockIdx.x * 1024 + threadIdx.x;
    if (i < n) {
        int off = offsets[i] - counts[i] + pbase;
        offsets[i] = off;
        cursors[i] = off;
    } else if (i == n) {
        offsets[n] = total;
    }
}

// ---------------- K3: fused QKV projection (f16 outputs) ----------------
__global__ __launch_bounds__(256, 4) void qkv_kernel(
        const float* __restrict__ x,
        const short* __restrict__ Whi, const short* __restrict__ Wlo,
        const float* __restrict__ ball,
        _Float16* __restrict__ Qb, _Float16* __restrict__ Kb, _Float16* __restrict__ Vb,
        int N) {
    __shared__ char lds[64 * AP * 2];
    const int t = threadIdx.x;
    const int m0 = blockIdx.x * 64;

#pragma unroll
    for (int i = 0; i < 4; ++i) {
        int g = t + i * 256;
        int row = g >> 4, c8 = g & 15;
        int grow = m0 + row;
        float4 f0 = {0.f,0.f,0.f,0.f}, f1 = {0.f,0.f,0.f,0.f};
        if (grow < N) {
            const float* p = x + (size_t)grow * 128 + c8 * 8;
            f0 = ntload4(p); f1 = ntload4(p + 4);
        }
        int4 v;
        v.x = cvt2(f0.x, f0.y); v.y = cvt2(f0.z, f0.w);
        v.z = cvt2(f1.x, f1.y); v.w = cvt2(f1.z, f1.w);
        *(int4*)(lds + row * (AP * 2) + c8 * 16) = v;
    }
    __syncthreads();

    const int w = t >> 6, lane = t & 63;
    const int r16 = lane & 15, g16 = lane >> 4;
    const int cb = w * 32;

    for (int ct = 0; ct < 3; ++ct) {
        const int colbase = ct * 128;
        f32x4 acc[4][2];
#pragma unroll
        for (int m = 0; m < 4; ++m)
#pragma unroll
            for (int n = 0; n < 2; ++n) acc[m][n] = (f32x4){0.f,0.f,0.f,0.f};

#pragma unroll
        for (int ks = 0; ks < 4; ++ks) {
            bf16x8 a[4];
#pragma unroll
            for (int m = 0; m < 4; ++m)
                a[m] = *(const bf16x8*)(lds + (m * 16 + r16) * (AP * 2) + ks * 64 + g16 * 16);
            bf16x8 bh2[2], bl2[2];
#pragma unroll
            for (int n = 0; n < 2; ++n) {
                int colg = colbase + cb + n * 16 + r16;
                bh2[n] = *(const bf16x8*)(Whi + colg * 128 + ks * 32 + g16 * 8);
                bl2[n] = *(const bf16x8*)(Wlo + colg * 128 + ks * 32 + g16 * 8);
            }
#pragma unroll
            for (int m = 0; m < 4; ++m)
#pragma unroll
                for (int n = 0; n < 2; ++n) {
                    acc[m][n] = __builtin_amdgcn_mfma_f32_16x16x32_bf16(a[m], bh2[n], acc[m][n], 0, 0, 0);
                    acc[m][n] = __builtin_amdgcn_mfma_f32_16x16x32_bf16(a[m], bl2[n], acc[m][n], 0, 0, 0);
                }
        }
        float bias[2];
#pragma unroll
        for (int n = 0; n < 2; ++n) bias[n] = ball[colbase + cb + n * 16 + r16];

        _Float16* outb = ct == 0 ? Qb : ct == 1 ? Kb : Vb;
#pragma unroll
        for (int m = 0; m < 4; ++m) {
            int grow = m0 + m * 16 + g16 * 4;
#pragma unroll
            for (int r = 0; r < 4; ++r) {
                if (grow + r < N) {
#pragma unroll
                    for (int n = 0; n < 2; ++n)
                        outb[(size_t)(grow + r) * 128 + cb + n * 16 + r16] =
                            (_Float16)(acc[m][n][r] + bias[n]);
                }
            }
        }
    }
}

// ---------------- K4: edge kernel, barrier-minimal ----------------
// A-fragments loaded straight from global (L1/L2-cached tile, loads interleave
// with MFMA); only the E exchange uses LDS; ONE __syncthreads total.
__global__ __launch_bounds__(256) void edge_kernel(
        const float* __restrict__ ea,
        const int* __restrict__ srcp, const int* __restrict__ dstp,
        const short* __restrict__ Whi, const short* __restrict__ Wlo,
        const float* __restrict__ ball,
        const _Float16* __restrict__ Qb, const _Float16* __restrict__ Kb,
        float* __restrict__ scores, int* __restrict__ cursors,
        int* __restrict__ ebuf, int NE) {
    __shared__ float e_lds[64 * EP];              // 33792 B
    __shared__ int slotArr[64];
    const int t = threadIdx.x;
    const int e0 = blockIdx.x * 64;

    // ---- top: edge indices + fused CSR scatter (overlaps MFMA phase) ----
    int sArr[2], dArr[2];
#pragma unroll
    for (int it = 0; it < 2; ++it) {
        int task = t + it * 256;                  // 0..511
        int el = task >> 3, h = task & 7;
        int eg = e0 + el;
        bool ok = eg < NE;
        int s = ok ? srcp[eg] : 0;
        int d = ok ? dstp[eg] : 0;
        sArr[it] = s; dArr[it] = d;
        if (ok && h == 0) {
            int pos = atomicAdd(&cursors[d], 1);
            ebuf[pos] = s * 128;                  // element offset into Vb (f16)
            slotArr[el] = pos;
        }
    }

    const int w = t >> 6, lane = t & 63;
    const int r16 = lane & 15, g16 = lane >> 4;
    const int cb = w * 32;

    f32x4 acc[4][2];
#pragma unroll
    for (int m = 0; m < 4; ++m)
#pragma unroll
        for (int n = 0; n < 2; ++n) acc[m][n] = (f32x4){0.f,0.f,0.f,0.f};

#pragma unroll
    for (int ks = 0; ks < 4; ++ks) {
        // A-fragment: 8 contiguous f32 from ea row (m*16+r16), cols ks*32+g16*8
        bf16x8 a[4];
#pragma unroll
        for (int m = 0; m < 4; ++m) {
            int grow = e0 + m * 16 + r16;
            float4 f0 = {0.f,0.f,0.f,0.f}, f1 = {0.f,0.f,0.f,0.f};
            if (grow < NE) {
                const float* p = ea + (size_t)grow * 128 + ks * 32 + g16 * 8;
                f0 = *(const float4*)p; f1 = *(const float4*)(p + 4);
            }
            bf16x8 av;
            int v0 = cvt2(f0.x, f0.y), v1 = cvt2(f0.z, f0.w);
            int v2 = cvt2(f1.x, f1.y), v3 = cvt2(f1.z, f1.w);
            __builtin_memcpy(&av, &v0, 4);
            __builtin_memcpy(((char*)&av) + 4, &v1, 4);
            __builtin_memcpy(((char*)&av) + 8, &v2, 4);
            __builtin_memcpy(((char*)&av) + 12, &v3, 4);
            a[m] = av;
        }
        bf16x8 bh2[2], bl2[2];
#pragma unroll
        for (int n = 0; n < 2; ++n) {
            int colg = 384 + cb + n * 16 + r16;   // We rows
            bh2[n] = *(const bf16x8*)(Whi + colg * 128 + ks * 32 + g16 * 8);
            bl2[n] = *(const bf16x8*)(Wlo + colg * 128 + ks * 32 + g16 * 8);
        }
#pragma unroll
        for (int m = 0; m < 4; ++m)
#pragma unroll
            for (int n = 0; n < 2; ++n) {
                acc[m][n] = __builtin_amdgcn_mfma_f32_16x16x32_bf16(a[m], bh2[n], acc[m][n], 0, 0, 0);
                acc[m][n] = __builtin_amdgcn_mfma_f32_16x16x32_bf16(a[m], bl2[n], acc[m][n], 0, 0, 0);
            }
    }
    float bias0 = ball[384 + cb + r16];
    float bias1 = ball[384 + cb + 16 + r16];

    // ---- E-store (no prior barrier needed: e_lds untouched until here) ----
#pragma unroll
    for (int m = 0; m < 4; ++m)
#pragma unroll
        for (int r = 0; r < 4; ++r) {
            int row = m * 16 + g16 * 4 + r;
            e_lds[row * EP + cb + r16]      = acc[m][0][r] + bias0;
            e_lds[row * EP + cb + 16 + r16] = acc[m][1][r] + bias1;
        }
    __syncthreads();                              // E-tile + slotArr visible

    // ---- epilogue: dot(E, K*Q)*scale, clamp, exp; write at CSR slot ----
#pragma unroll
    for (int it = 0; it < 2; ++it) {
        int task = t + it * 256;
        int el = task >> 3, h = task & 7;
        int eg = e0 + el;
        if (eg < NE) {
            const f16x8* Kp = (const f16x8*)(Kb + (size_t)sArr[it] * 128 + h * 16);
            const f16x8* Qp = (const f16x8*)(Qb + (size_t)dArr[it] * 128 + h * 16);
            f16x8 k0 = Kp[0], k1 = Kp[1];
            f16x8 q0 = Qp[0], q1 = Qp[1];
            float dot = 0.f;
#pragma unroll
            for (int jj = 0; jj < 2; ++jj) {
                f32x4 ev0 = *(const f32x4*)(e_lds + el * EP + h * 16 + jj * 8);
                f32x4 ev1 = *(const f32x4*)(e_lds + el * EP + h * 16 + jj * 8 + 4);
                const f16x8& kk = jj == 0 ? k0 : k1;
                const f16x8& qq = jj == 0 ? q0 : q1;
#pragma unroll
                for (int r = 0; r < 4; ++r) {
                    dot += ev0[r] * (float)kk[r] * (float)qq[r];
                    dot += ev1[r] * (float)kk[r + 4] * (float)qq[r + 4];
                }
            }
            float sv = fminf(fmaxf(dot * 0.25f, -5.0f), 5.0f);
            int slot = slotArr[el];               // random 32B writes: fire-and-forget
            scores[(size_t)slot * 8 + h] = __expf(sv);
        }
    }
}

// ---------------- K5: gather/aggregate (f16 V rows) ----------------
// ebuf + scores reads SEQUENTIAL (CSR order); only V rows random.
__global__ __launch_bounds__(256) void gather_kernel(
        const int* __restrict__ offsets, const int* __restrict__ ebuf,
        const float* __restrict__ scores, const _Float16* __restrict__ Vb,
        float* __restrict__ out, int N) {
    int node = blockIdx.x * 8 + (threadIdx.x >> 5);
    int c4 = threadIdx.x & 31;                    // 4-col slot: cols [c4*4, c4*4+4)
    if (node >= N) return;
    int h = c4 >> 2;                              // head for these 4 cols
    int beg = offsets[node], end = offsets[node + 1];
    f32x4 a0 = {0.f,0.f,0.f,0.f}, a1 = a0, a2 = a0, a3 = a0;
    int j = beg;
    auto vload = [&](int off) -> f32x4 {
        f16x4 v = *(const f16x4*)(Vb + off + c4 * 4);
        return (f32x4){(float)v[0], (float)v[1], (float)v[2], (float)v[3]};
    };
    for (; j + 8 <= end; j += 8) {
        int s0 = ebuf[j],     s1 = ebuf[j + 1], s2 = ebuf[j + 2], s3 = ebuf[j + 3];
        int s4 = ebuf[j + 4], s5 = ebuf[j + 5], s6 = ebuf[j + 6], s7 = ebuf[j + 7];
        f32x4 v0 = vload(s0), v1 = vload(s1), v2 = vload(s2), v3 = vload(s3);
        f32x4 v4 = vload(s4), v5 = vload(s5), v6 = vload(s6), v7 = vload(s7);
        a0 += scores[(size_t)(j    ) * 8 + h] * v0;
        a1 += scores[(size_t)(j + 1) * 8 + h] * v1;
        a2 += scores[(size_t)(j + 2) * 8 + h] * v2;
        a3 += scores[(size_t)(j + 3) * 8 + h] * v3;
        a0 += scores[(size_t)(j + 4) * 8 + h] * v4;
        a1 += scores[(size_t)(j + 5) * 8 + h] * v5;
        a2 += scores[(size_t)(j + 6) * 8 + h] * v6;
        a3 += scores[(size_t)(j + 7) * 8 + h] * v7;
    }
    for (; j < end; ++j) {
        a0 += scores[(size_t)j * 8 + h] * vload(ebuf[j]);
    }
    f32x4 sum = (a0 + a1) + (a2 + a3);
    *(f32x4*)(out + (size_t)node * 128 + c4 * 4) = sum;
}

// ---------------- launcher ----------------
extern "C" void kernel_launch(void* const* d_in, const int* in_sizes, int n_in,
                              void* d_out, int out_size, void* d_ws, size_t ws_size,
                              hipStream_t stream) {
    const float* x   = (const float*)d_in[0];
    const float* ea  = (const float*)d_in[1];
    const int* eidx  = (const int*)d_in[2];
    const float* Wq  = (const float*)d_in[4];  const float* bq = (const float*)d_in[5];
    const float* Wk  = (const float*)d_in[6];  const float* bk = (const float*)d_in[7];
    const float* We  = (const float*)d_in[8];  const float* be = (const float*)d_in[9];
    const float* Wv  = (const float*)d_in[10]; const float* bv = (const float*)d_in[11];
    const int N  = in_sizes[0] / 128;
    const int NE = in_sizes[2] / 2;
    const int* srcp = eidx;
    const int* dstp = eidx + NE;
    float* out = (float*)d_out;

    char* ws = (char*)d_ws;
    size_t o = 0;
    auto alloc = [&](size_t b) { size_t r = o; o += (b + 255) & ~(size_t)255; return r; };
    _Float16* Qb   = (_Float16*)(ws + alloc((size_t)N * 128 * 2));
    _Float16* Kb   = (_Float16*)(ws + alloc((size_t)N * 128 * 2));
    _Float16* Vb   = (_Float16*)(ws + alloc((size_t)N * 128 * 2));
    float* scores  = (float*)(ws + alloc((size_t)NE * 8 * 4));
    short* Whi     = (short*)(ws + alloc(512 * 128 * 2));
    short* Wlo     = (short*)(ws + alloc(512 * 128 * 2));
    float* ball    = (float*)(ws + alloc(512 * 4));
    int* counts    = (int*)(ws + alloc((size_t)(N + 1) * 4));
    int* offsets   = (int*)(ws + alloc((size_t)(N + 1) * 4));
    int* cursors   = (int*)(ws + alloc((size_t)N * 4));
    int* ebuf      = (int*)(ws + alloc((size_t)NE * 4));
    int* partials  = (int*)(ws + alloc(64 * 4));
    (void)ws_size; (void)n_in; (void)out_size;

    (void)hipMemsetAsync(counts, 0, (size_t)(N + 1) * 4, stream);

    convert_weights<<<256, 256, 0, stream>>>(Wq, bq, Wk, bk, We, be, Wv, bv,
                                             dstp, NE, Whi, Wlo, ball, counts);

    int nb = (N + 1023) / 1024;
    scan1_kernel<<<nb, 1024, 0, stream>>>(counts, offsets, partials, N);
    scanB_kernel<<<nb, 1024, 0, stream>>>(counts, offsets, cursors, partials, N, NE);

    qkv_kernel<<<(N + 63) / 64, 256, 0, stream>>>(x, Whi, Wlo, ball, Qb, Kb, Vb, N);

    edge_kernel<<<(NE + 63) / 64, 256, 0, stream>>>(ea, srcp, dstp, Whi, Wlo, ball,
                                                    Qb, Kb, scores, cursors, ebuf, NE);

    gather_kernel<<<(N + 7) / 8, 256, 0, stream>>>(offsets, ebuf, scores, Vb, out, N);
}

// Round 14
// 302.825 us; speedup vs baseline: 1.6549x; 1.6549x over previous
//
#include <hip/hip_runtime.h>
#include <hip/hip_bf16.h>
#include <hip/hip_fp16.h>
#include <cstdint>

// Exphormer attention, MI355X.
// K1 convert weights (fp32 -> f16) + dst histogram ->
// K2 scan1 + scanB (CSR offsets/cursors) ->
// K3 fused QKV projection (f16 MFMA single-weight, f16 outputs) ->
// K4 edge kernel (R11 structure): f16 LDS A-tile staging, hoisted f16 We
//    in registers (32 VGPRs), E-tile f32 in LDS, CSR-slot score writes +
//    fused scatter ->
// K5 gather: out[dst] = sum score * V[src]; ebuf+scores sequential, V random.

typedef float    f32x4  __attribute__((ext_vector_type(4)));
typedef int      i32x4  __attribute__((ext_vector_type(4)));
typedef _Float16 f16x8  __attribute__((ext_vector_type(8)));
typedef _Float16 f16x4  __attribute__((ext_vector_type(4)));

#define AP 136   // A-tile row stride (f16 elems): 64x136x2 = 17408 B
#define EP 132   // E-tile row stride (f32 elems):  64x132x4 = 33792 B

// packed f32x2 -> f16x2 (RNE)
__device__ __forceinline__ int cvt2h(float a, float b) {
    float2 t; t.x = a; t.y = b;
    __half2 h = __float22half2_rn(t);
    int r; __builtin_memcpy(&r, &h, 4);
    return r;
}
// non-temporal 16B load (streaming data: don't pollute caches)
__device__ __forceinline__ float4 ntload4(const float* p) {
    i32x4 r = __builtin_nontemporal_load((const i32x4*)p);
    float4 f; __builtin_memcpy(&f, &r, 16);
    return f;
}

// ---------------- K1: weight conversion (f16) + dst histogram ----------------
// Wf rows: [0:128)=Wq, [128:256)=Wk, [256:384)=Wv, [384:512)=We
__global__ __launch_bounds__(256) void convert_weights(
        const float* __restrict__ Wq, const float* __restrict__ bq,
        const float* __restrict__ Wk, const float* __restrict__ bk,
        const float* __restrict__ We, const float* __restrict__ be,
        const float* __restrict__ Wv, const float* __restrict__ bv,
        const int* __restrict__ dstp, int NE,
        _Float16* __restrict__ Wf, float* __restrict__ ball,
        int* __restrict__ counts) {
    int idx = blockIdx.x * 256 + threadIdx.x;     // 0..65535
    int wrow = idx >> 7;
    int k = idx & 127;
    int which = wrow >> 7;
    int r = wrow & 127;
    const float* Wsrc = which == 0 ? Wq : which == 1 ? Wk : which == 2 ? Wv : We;
    Wf[idx] = (_Float16)Wsrc[r * 128 + k];
    if (idx < 512) {
        int wh = idx >> 7; int rr = idx & 127;
        const float* bsrc = wh == 0 ? bq : wh == 1 ? bk : wh == 2 ? bv : be;
        ball[idx] = bsrc[rr];
    }
    // fused dst histogram (grid-stride over edges)
    for (int i = idx; i < NE; i += 65536)
        atomicAdd(&counts[dstp[i]], 1);
}

// ---------------- K2: CSR scans ----------------
__global__ __launch_bounds__(1024) void scan1_kernel(const int* __restrict__ counts,
                                                     int* __restrict__ incl,
                                                     int* __restrict__ partials, int n) {
    __shared__ int sh[1024];
    int t = threadIdx.x;
    int i = blockIdx.x * 1024 + t;
    sh[t] = (i < n) ? counts[i] : 0;
    for (int off = 1; off < 1024; off <<= 1) {
        __syncthreads();
        int xv = (t >= off) ? sh[t - off] : 0;
        __syncthreads();
        sh[t] += xv;
    }
    __syncthreads();
    if (i < n) incl[i] = sh[t];
    if (t == 1023) partials[blockIdx.x] = sh[1023];
}

// fused scan2+scan3
__global__ __launch_bounds__(1024) void scanB_kernel(const int* __restrict__ counts,
                                                     int* __restrict__ offsets,
                                                     int* __restrict__ cursors,
                                                     const int* __restrict__ partials,
                                                     int n, int total) {
    int pbase = 0;
    for (int b = 0; b < (int)blockIdx.x; ++b) pbase += partials[b];
    int i = blockIdx.x * 1024 + threadIdx.x;
    if (i < n) {
        int off = offsets[i] - counts[i] + pbase;
        offsets[i] = off;
        cursors[i] = off;
    } else if (i == n) {
        offsets[n] = total;
    }
}

// ---------------- K3: fused QKV projection (f16 MFMA, f16 outputs) ----------------
__global__ __launch_bounds__(256, 4) void qkv_kernel(
        const float* __restrict__ x,
        const _Float16* __restrict__ Wf, const float* __restrict__ ball,
        _Float16* __restrict__ Qb, _Float16* __restrict__ Kb, _Float16* __restrict__ Vb,
        int N) {
    __shared__ char lds[64 * AP * 2];
    const int t = threadIdx.x;
    const int m0 = blockIdx.x * 64;

    // stage x tile -> f16 LDS
#pragma unroll
    for (int i = 0; i < 4; ++i) {
        int g = t + i * 256;
        int row = g >> 4, c8 = g & 15;
        int grow = m0 + row;
        float4 f0 = {0.f,0.f,0.f,0.f}, f1 = {0.f,0.f,0.f,0.f};
        if (grow < N) {
            const float* p = x + (size_t)grow * 128 + c8 * 8;
            f0 = ntload4(p); f1 = ntload4(p + 4);
        }
        int4 v;
        v.x = cvt2h(f0.x, f0.y); v.y = cvt2h(f0.z, f0.w);
        v.z = cvt2h(f1.x, f1.y); v.w = cvt2h(f1.z, f1.w);
        *(int4*)(lds + row * (AP * 2) + c8 * 16) = v;
    }
    __syncthreads();

    const int w = t >> 6, lane = t & 63;
    const int r16 = lane & 15, g16 = lane >> 4;
    const int cb = w * 32;

    for (int ct = 0; ct < 3; ++ct) {
        const int colbase = ct * 128;
        f32x4 acc[4][2];
#pragma unroll
        for (int m = 0; m < 4; ++m)
#pragma unroll
            for (int n = 0; n < 2; ++n) acc[m][n] = (f32x4){0.f,0.f,0.f,0.f};

#pragma unroll
        for (int ks = 0; ks < 4; ++ks) {
            f16x8 a[4];
#pragma unroll
            for (int m = 0; m < 4; ++m)
                a[m] = *(const f16x8*)(lds + (m * 16 + r16) * (AP * 2) + ks * 64 + g16 * 16);
            f16x8 bw[2];
#pragma unroll
            for (int n = 0; n < 2; ++n) {
                int colg = colbase + cb + n * 16 + r16;
                bw[n] = *(const f16x8*)(Wf + colg * 128 + ks * 32 + g16 * 8);
            }
#pragma unroll
            for (int m = 0; m < 4; ++m)
#pragma unroll
                for (int n = 0; n < 2; ++n)
                    acc[m][n] = __builtin_amdgcn_mfma_f32_16x16x32_f16(a[m], bw[n], acc[m][n], 0, 0, 0);
        }
        float bias[2];
#pragma unroll
        for (int n = 0; n < 2; ++n) bias[n] = ball[colbase + cb + n * 16 + r16];

        _Float16* outb = ct == 0 ? Qb : ct == 1 ? Kb : Vb;
#pragma unroll
        for (int m = 0; m < 4; ++m) {
            int grow = m0 + m * 16 + g16 * 4;
#pragma unroll
            for (int r = 0; r < 4; ++r) {
                if (grow + r < N) {
#pragma unroll
                    for (int n = 0; n < 2; ++n)
                        outb[(size_t)(grow + r) * 128 + cb + n * 16 + r16] =
                            (_Float16)(acc[m][n][r] + bias[n]);
                }
            }
        }
    }
}

// ---------------- K4: edge kernel (R11 structure, f16 MFMA, hoisted We) ----------------
__global__ __launch_bounds__(256) void edge_kernel(
        const float* __restrict__ ea,
        const int* __restrict__ srcp, const int* __restrict__ dstp,
        const _Float16* __restrict__ Wf, const float* __restrict__ ball,
        const _Float16* __restrict__ Qb, const _Float16* __restrict__ Kb,
        float* __restrict__ scores, int* __restrict__ cursors,
        int* __restrict__ ebuf, int NE) {
    __shared__ char lds[64 * EP * 4];             // A-tile (f16) unioned with E f32 tile
    __shared__ int slotArr[64];
    const int t = threadIdx.x;
    const int e0 = blockIdx.x * 64;

    // ---- top: edge indices + fused CSR scatter; publish slot via LDS ----
    int sArr[2], dArr[2];
#pragma unroll
    for (int it = 0; it < 2; ++it) {
        int task = t + it * 256;                  // 0..511
        int el = task >> 3, h = task & 7;
        int eg = e0 + el;
        bool ok = eg < NE;
        int s = ok ? srcp[eg] : 0;
        int d = ok ? dstp[eg] : 0;
        sArr[it] = s; dArr[it] = d;
        if (ok && h == 0) {
            int pos = atomicAdd(&cursors[d], 1);
            ebuf[pos] = s * 128;                  // element offset into Vb (f16)
            slotArr[el] = pos;
        }
    }

    const int w = t >> 6, lane = t & 63;
    const int r16 = lane & 15, g16 = lane >> 4;
    const int cb = w * 32;

    // hoist the full per-wave We operand: 8 frags = 32 VGPRs (f16 single)
    f16x8 bw[4][2];
#pragma unroll
    for (int ks = 0; ks < 4; ++ks)
#pragma unroll
        for (int n = 0; n < 2; ++n) {
            int colg = 384 + cb + n * 16 + r16;   // We rows
            bw[ks][n] = *(const f16x8*)(Wf + colg * 128 + ks * 32 + g16 * 8);
        }

    // ---- stage ea tile -> f16 LDS (sequential stream) ----
#pragma unroll
    for (int i = 0; i < 4; ++i) {
        int g = t + i * 256;
        int row = g >> 4, c8 = g & 15;
        int grow = e0 + row;
        float4 f0 = {0.f,0.f,0.f,0.f}, f1 = {0.f,0.f,0.f,0.f};
        if (grow < NE) {
            const float* p = ea + (size_t)grow * 128 + c8 * 8;
            f0 = ntload4(p); f1 = ntload4(p + 4);
        }
        int4 v;
        v.x = cvt2h(f0.x, f0.y); v.y = cvt2h(f0.z, f0.w);
        v.z = cvt2h(f1.x, f1.y); v.w = cvt2h(f1.z, f1.w);
        *(int4*)(lds + row * (AP * 2) + c8 * 16) = v;
    }
    __syncthreads();

    f32x4 acc[4][2];
#pragma unroll
    for (int m = 0; m < 4; ++m)
#pragma unroll
        for (int n = 0; n < 2; ++n) acc[m][n] = (f32x4){0.f,0.f,0.f,0.f};

#pragma unroll
    for (int ks = 0; ks < 4; ++ks) {
        f16x8 a[4];
#pragma unroll
        for (int m = 0; m < 4; ++m)
            a[m] = *(const f16x8*)(lds + (m * 16 + r16) * (AP * 2) + ks * 64 + g16 * 16);
#pragma unroll
        for (int m = 0; m < 4; ++m)
#pragma unroll
            for (int n = 0; n < 2; ++n)
                acc[m][n] = __builtin_amdgcn_mfma_f32_16x16x32_f16(a[m], bw[ks][n], acc[m][n], 0, 0, 0);
    }
    float bias0 = ball[384 + cb + r16];
    float bias1 = ball[384 + cb + 16 + r16];

    __syncthreads();                              // all waves done reading A-tile
    float* e_lds = (float*)lds;                   // reuse as f32 E tile [64][EP]
#pragma unroll
    for (int m = 0; m < 4; ++m)
#pragma unroll
        for (int r = 0; r < 4; ++r) {
            int row = m * 16 + g16 * 4 + r;
            e_lds[row * EP + cb + r16]      = acc[m][0][r] + bias0;
            e_lds[row * EP + cb + 16 + r16] = acc[m][1][r] + bias1;
        }
    __syncthreads();

    // ---- epilogue: dot(E, K*Q)*scale, clamp, exp; write at CSR slot ----
#pragma unroll
    for (int it = 0; it < 2; ++it) {
        int task = t + it * 256;
        int el = task >> 3, h = task & 7;
        int eg = e0 + el;
        if (eg < NE) {
            const f16x8* Kp = (const f16x8*)(Kb + (size_t)sArr[it] * 128 + h * 16);
            const f16x8* Qp = (const f16x8*)(Qb + (size_t)dArr[it] * 128 + h * 16);
            f16x8 k0 = Kp[0], k1 = Kp[1];
            f16x8 q0 = Qp[0], q1 = Qp[1];
            float dot = 0.f;
#pragma unroll
            for (int jj = 0; jj < 2; ++jj) {
                f32x4 ev0 = *(const f32x4*)(e_lds + el * EP + h * 16 + jj * 8);
                f32x4 ev1 = *(const f32x4*)(e_lds + el * EP + h * 16 + jj * 8 + 4);
                const f16x8& kk = jj == 0 ? k0 : k1;
                const f16x8& qq = jj == 0 ? q0 : q1;
#pragma unroll
                for (int r = 0; r < 4; ++r) {
                    dot += ev0[r] * (float)kk[r] * (float)qq[r];
                    dot += ev1[r] * (float)kk[r + 4] * (float)qq[r + 4];
                }
            }
            float sv = fminf(fmaxf(dot * 0.25f, -5.0f), 5.0f);
            int slot = slotArr[el];               // random 32B writes: fire-and-forget
            scores[(size_t)slot * 8 + h] = __expf(sv);
        }
    }
}

// ---------------- K5: gather/aggregate (f16 V rows) ----------------
// ebuf + scores reads SEQUENTIAL (CSR order); only V rows random.
__global__ __launch_bounds__(256) void gather_kernel(
        const int* __restrict__ offsets, const int* __restrict__ ebuf,
        const float* __restrict__ scores, const _Float16* __restrict__ Vb,
        float* __restrict__ out, int N) {
    int node = blockIdx.x * 8 + (threadIdx.x >> 5);
    int c4 = threadIdx.x & 31;                    // 4-col slot: cols [c4*4, c4*4+4)
    if (node >= N) return;
    int h = c4 >> 2;                              // head for these 4 cols
    int beg = offsets[node], end = offsets[node + 1];
    f32x4 a0 = {0.f,0.f,0.f,0.f}, a1 = a0, a2 = a0, a3 = a0;
    int j = beg;
    auto vload = [&](int off) -> f32x4 {
        f16x4 v = *(const f16x4*)(Vb + off + c4 * 4);
        return (f32x4){(float)v[0], (float)v[1], (float)v[2], (float)v[3]};
    };
    for (; j + 8 <= end; j += 8) {
        int s0 = ebuf[j],     s1 = ebuf[j + 1], s2 = ebuf[j + 2], s3 = ebuf[j + 3];
        int s4 = ebuf[j + 4], s5 = ebuf[j + 5], s6 = ebuf[j + 6], s7 = ebuf[j + 7];
        f32x4 v0 = vload(s0), v1 = vload(s1), v2 = vload(s2), v3 = vload(s3);
        f32x4 v4 = vload(s4), v5 = vload(s5), v6 = vload(s6), v7 = vload(s7);
        a0 += scores[(size_t)(j    ) * 8 + h] * v0;
        a1 += scores[(size_t)(j + 1) * 8 + h] * v1;
        a2 += scores[(size_t)(j + 2) * 8 + h] * v2;
        a3 += scores[(size_t)(j + 3) * 8 + h] * v3;
        a0 += scores[(size_t)(j + 4) * 8 + h] * v4;
        a1 += scores[(size_t)(j + 5) * 8 + h] * v5;
        a2 += scores[(size_t)(j + 6) * 8 + h] * v6;
        a3 += scores[(size_t)(j + 7) * 8 + h] * v7;
    }
    for (; j < end; ++j) {
        a0 += scores[(size_t)j * 8 + h] * vload(ebuf[j]);
    }
    f32x4 sum = (a0 + a1) + (a2 + a3);
    *(f32x4*)(out + (size_t)node * 128 + c4 * 4) = sum;
}

// ---------------- launcher ----------------
extern "C" void kernel_launch(void* const* d_in, const int* in_sizes, int n_in,
                              void* d_out, int out_size, void* d_ws, size_t ws_size,
                              hipStream_t stream) {
    const float* x   = (const float*)d_in[0];
    const float* ea  = (const float*)d_in[1];
    const int* eidx  = (const int*)d_in[2];
    const float* Wq  = (const float*)d_in[4];  const float* bq = (const float*)d_in[5];
    const float* Wk  = (const float*)d_in[6];  const float* bk = (const float*)d_in[7];
    const float* We  = (const float*)d_in[8];  const float* be = (const float*)d_in[9];
    const float* Wv  = (const float*)d_in[10]; const float* bv = (const float*)d_in[11];
    const int N  = in_sizes[0] / 128;
    const int NE = in_sizes[2] / 2;
    const int* srcp = eidx;
    const int* dstp = eidx + NE;
    float* out = (float*)d_out;

    char* ws = (char*)d_ws;
    size_t o = 0;
    auto alloc = [&](size_t b) { size_t r = o; o += (b + 255) & ~(size_t)255; return r; };
    _Float16* Qb   = (_Float16*)(ws + alloc((size_t)N * 128 * 2));
    _Float16* Kb   = (_Float16*)(ws + alloc((size_t)N * 128 * 2));
    _Float16* Vb   = (_Float16*)(ws + alloc((size_t)N * 128 * 2));
    float* scores  = (float*)(ws + alloc((size_t)NE * 8 * 4));
    _Float16* Wf   = (_Float16*)(ws + alloc(512 * 128 * 2));
    float* ball    = (float*)(ws + alloc(512 * 4));
    int* counts    = (int*)(ws + alloc((size_t)(N + 1) * 4));
    int* offsets   = (int*)(ws + alloc((size_t)(N + 1) * 4));
    int* cursors   = (int*)(ws + alloc((size_t)N * 4));
    int* ebuf      = (int*)(ws + alloc((size_t)NE * 4));
    int* partials  = (int*)(ws + alloc(64 * 4));
    (void)ws_size; (void)n_in; (void)out_size;

    (void)hipMemsetAsync(counts, 0, (size_t)(N + 1) * 4, stream);

    convert_weights<<<256, 256, 0, stream>>>(Wq, bq, Wk, bk, We, be, Wv, bv,
                                             dstp, NE, Wf, ball, counts);

    int nb = (N + 1023) / 1024;
    scan1_kernel<<<nb, 1024, 0, stream>>>(counts, offsets, partials, N);
    scanB_kernel<<<nb, 1024, 0, stream>>>(counts, offsets, cursors, partials, N, NE);

    qkv_kernel<<<(N + 63) / 64, 256, 0, stream>>>(x, Wf, ball, Qb, Kb, Vb, N);

    edge_kernel<<<(NE + 63) / 64, 256, 0, stream>>>(ea, srcp, dstp, Wf, ball,
                                                    Qb, Kb, scores, cursors, ebuf, NE);

    gather_kernel<<<(N + 7) / 8, 256, 0, stream>>>(offsets, ebuf, scores, Vb, out, N);
}

// Round 15
// 295.632 us; speedup vs baseline: 1.6952x; 1.0243x over previous
//
#include <hip/hip_runtime.h>
#include <hip/hip_bf16.h>
#include <hip/hip_fp16.h>
#include <cstdint>

// Exphormer attention, MI355X.
// K1 convert weights (fp32 -> f16) + dst histogram ->
// K2 scan1 + scanB (CSR offsets/cursors) ->
// K3 fused QKV projection (f16 MFMA single-weight, f16 outputs) ->
// K4 edge kernel: f16 LDS A-tile staging, hoisted f16 We (32 VGPRs),
//    E-tile f32 in LDS, f16 scores at CSR slot + fused scatter ->
// K5 gather: 16 thr/node, f16x8 V loads; ebuf+scores sequential, V random.

typedef float    f32x4  __attribute__((ext_vector_type(4)));
typedef int      i32x4  __attribute__((ext_vector_type(4)));
typedef _Float16 f16x8  __attribute__((ext_vector_type(8)));

#define AP 136   // A-tile row stride (f16 elems): 64x136x2 = 17408 B
#define EP 132   // E-tile row stride (f32 elems):  64x132x4 = 33792 B

// packed f32x2 -> f16x2 (RNE)
__device__ __forceinline__ int cvt2h(float a, float b) {
    float2 t; t.x = a; t.y = b;
    __half2 h = __float22half2_rn(t);
    int r; __builtin_memcpy(&r, &h, 4);
    return r;
}
// non-temporal 16B load (streaming data: don't pollute caches)
__device__ __forceinline__ float4 ntload4(const float* p) {
    i32x4 r = __builtin_nontemporal_load((const i32x4*)p);
    float4 f; __builtin_memcpy(&f, &r, 16);
    return f;
}

// ---------------- K1: weight conversion (f16) + dst histogram ----------------
// Wf rows: [0:128)=Wq, [128:256)=Wk, [256:384)=Wv, [384:512)=We
__global__ __launch_bounds__(256) void convert_weights(
        const float* __restrict__ Wq, const float* __restrict__ bq,
        const float* __restrict__ Wk, const float* __restrict__ bk,
        const float* __restrict__ We, const float* __restrict__ be,
        const float* __restrict__ Wv, const float* __restrict__ bv,
        const int* __restrict__ dstp, int NE,
        _Float16* __restrict__ Wf, float* __restrict__ ball,
        int* __restrict__ counts) {
    int idx = blockIdx.x * 256 + threadIdx.x;     // 0..65535
    int wrow = idx >> 7;
    int k = idx & 127;
    int which = wrow >> 7;
    int r = wrow & 127;
    const float* Wsrc = which == 0 ? Wq : which == 1 ? Wk : which == 2 ? Wv : We;
    Wf[idx] = (_Float16)Wsrc[r * 128 + k];
    if (idx < 512) {
        int wh = idx >> 7; int rr = idx & 127;
        const float* bsrc = wh == 0 ? bq : wh == 1 ? bk : wh == 2 ? bv : be;
        ball[idx] = bsrc[rr];
    }
    // fused dst histogram (grid-stride over edges)
    for (int i = idx; i < NE; i += 65536)
        atomicAdd(&counts[dstp[i]], 1);
}

// ---------------- K2: CSR scans ----------------
__global__ __launch_bounds__(1024) void scan1_kernel(const int* __restrict__ counts,
                                                     int* __restrict__ incl,
                                                     int* __restrict__ partials, int n) {
    __shared__ int sh[1024];
    int t = threadIdx.x;
    int i = blockIdx.x * 1024 + t;
    sh[t] = (i < n) ? counts[i] : 0;
    for (int off = 1; off < 1024; off <<= 1) {
        __syncthreads();
        int xv = (t >= off) ? sh[t - off] : 0;
        __syncthreads();
        sh[t] += xv;
    }
    __syncthreads();
    if (i < n) incl[i] = sh[t];
    if (t == 1023) partials[blockIdx.x] = sh[1023];
}

// fused scan2+scan3
__global__ __launch_bounds__(1024) void scanB_kernel(const int* __restrict__ counts,
                                                     int* __restrict__ offsets,
                                                     int* __restrict__ cursors,
                                                     const int* __restrict__ partials,
                                                     int n, int total) {
    int pbase = 0;
    for (int b = 0; b < (int)blockIdx.x; ++b) pbase += partials[b];
    int i = blockIdx.x * 1024 + threadIdx.x;
    if (i < n) {
        int off = offsets[i] - counts[i] + pbase;
        offsets[i] = off;
        cursors[i] = off;
    } else if (i == n) {
        offsets[n] = total;
    }
}

// ---------------- K3: fused QKV projection (f16 MFMA, f16 outputs) ----------------
__global__ __launch_bounds__(256, 4) void qkv_kernel(
        const float* __restrict__ x,
        const _Float16* __restrict__ Wf, const float* __restrict__ ball,
        _Float16* __restrict__ Qb, _Float16* __restrict__ Kb, _Float16* __restrict__ Vb,
        int N) {
    __shared__ char lds[64 * AP * 2];
    const int t = threadIdx.x;
    const int m0 = blockIdx.x * 64;

    // stage x tile -> f16 LDS
#pragma unroll
    for (int i = 0; i < 4; ++i) {
        int g = t + i * 256;
        int row = g >> 4, c8 = g & 15;
        int grow = m0 + row;
        float4 f0 = {0.f,0.f,0.f,0.f}, f1 = {0.f,0.f,0.f,0.f};
        if (grow < N) {
            const float* p = x + (size_t)grow * 128 + c8 * 8;
            f0 = ntload4(p); f1 = ntload4(p + 4);
        }
        int4 v;
        v.x = cvt2h(f0.x, f0.y); v.y = cvt2h(f0.z, f0.w);
        v.z = cvt2h(f1.x, f1.y); v.w = cvt2h(f1.z, f1.w);
        *(int4*)(lds + row * (AP * 2) + c8 * 16) = v;
    }
    __syncthreads();

    const int w = t >> 6, lane = t & 63;
    const int r16 = lane & 15, g16 = lane >> 4;
    const int cb = w * 32;

    for (int ct = 0; ct < 3; ++ct) {
        const int colbase = ct * 128;
        f32x4 acc[4][2];
#pragma unroll
        for (int m = 0; m < 4; ++m)
#pragma unroll
            for (int n = 0; n < 2; ++n) acc[m][n] = (f32x4){0.f,0.f,0.f,0.f};

#pragma unroll
        for (int ks = 0; ks < 4; ++ks) {
            f16x8 a[4];
#pragma unroll
            for (int m = 0; m < 4; ++m)
                a[m] = *(const f16x8*)(lds + (m * 16 + r16) * (AP * 2) + ks * 64 + g16 * 16);
            f16x8 bw[2];
#pragma unroll
            for (int n = 0; n < 2; ++n) {
                int colg = colbase + cb + n * 16 + r16;
                bw[n] = *(const f16x8*)(Wf + colg * 128 + ks * 32 + g16 * 8);
            }
#pragma unroll
            for (int m = 0; m < 4; ++m)
#pragma unroll
                for (int n = 0; n < 2; ++n)
                    acc[m][n] = __builtin_amdgcn_mfma_f32_16x16x32_f16(a[m], bw[n], acc[m][n], 0, 0, 0);
        }
        float bias[2];
#pragma unroll
        for (int n = 0; n < 2; ++n) bias[n] = ball[colbase + cb + n * 16 + r16];

        _Float16* outb = ct == 0 ? Qb : ct == 1 ? Kb : Vb;
#pragma unroll
        for (int m = 0; m < 4; ++m) {
            int grow = m0 + m * 16 + g16 * 4;
#pragma unroll
            for (int r = 0; r < 4; ++r) {
                if (grow + r < N) {
#pragma unroll
                    for (int n = 0; n < 2; ++n)
                        outb[(size_t)(grow + r) * 128 + cb + n * 16 + r16] =
                            (_Float16)(acc[m][n][r] + bias[n]);
                }
            }
        }
    }
}

// ---------------- K4: edge kernel (f16 MFMA, hoisted We, f16 scores) ----------------
__global__ __launch_bounds__(256) void edge_kernel(
        const float* __restrict__ ea,
        const int* __restrict__ srcp, const int* __restrict__ dstp,
        const _Float16* __restrict__ Wf, const float* __restrict__ ball,
        const _Float16* __restrict__ Qb, const _Float16* __restrict__ Kb,
        _Float16* __restrict__ scores, int* __restrict__ cursors,
        int* __restrict__ ebuf, int NE) {
    __shared__ char lds[64 * EP * 4];             // A-tile (f16) unioned with E f32 tile
    __shared__ int slotArr[64];
    const int t = threadIdx.x;
    const int e0 = blockIdx.x * 64;

    // ---- top: edge indices + fused CSR scatter; publish slot via LDS ----
    int sArr[2], dArr[2];
#pragma unroll
    for (int it = 0; it < 2; ++it) {
        int task = t + it * 256;                  // 0..511
        int el = task >> 3, h = task & 7;
        int eg = e0 + el;
        bool ok = eg < NE;
        int s = ok ? srcp[eg] : 0;
        int d = ok ? dstp[eg] : 0;
        sArr[it] = s; dArr[it] = d;
        if (ok && h == 0) {
            int pos = atomicAdd(&cursors[d], 1);
            ebuf[pos] = s * 128;                  // element offset into Vb (f16)
            slotArr[el] = pos;
        }
    }

    const int w = t >> 6, lane = t & 63;
    const int r16 = lane & 15, g16 = lane >> 4;
    const int cb = w * 32;

    // hoist the full per-wave We operand: 8 frags = 32 VGPRs (f16 single)
    f16x8 bw[4][2];
#pragma unroll
    for (int ks = 0; ks < 4; ++ks)
#pragma unroll
        for (int n = 0; n < 2; ++n) {
            int colg = 384 + cb + n * 16 + r16;   // We rows
            bw[ks][n] = *(const f16x8*)(Wf + colg * 128 + ks * 32 + g16 * 8);
        }

    // ---- stage ea tile -> f16 LDS (sequential stream) ----
#pragma unroll
    for (int i = 0; i < 4; ++i) {
        int g = t + i * 256;
        int row = g >> 4, c8 = g & 15;
        int grow = e0 + row;
        float4 f0 = {0.f,0.f,0.f,0.f}, f1 = {0.f,0.f,0.f,0.f};
        if (grow < NE) {
            const float* p = ea + (size_t)grow * 128 + c8 * 8;
            f0 = ntload4(p); f1 = ntload4(p + 4);
        }
        int4 v;
        v.x = cvt2h(f0.x, f0.y); v.y = cvt2h(f0.z, f0.w);
        v.z = cvt2h(f1.x, f1.y); v.w = cvt2h(f1.z, f1.w);
        *(int4*)(lds + row * (AP * 2) + c8 * 16) = v;
    }
    __syncthreads();

    f32x4 acc[4][2];
#pragma unroll
    for (int m = 0; m < 4; ++m)
#pragma unroll
        for (int n = 0; n < 2; ++n) acc[m][n] = (f32x4){0.f,0.f,0.f,0.f};

#pragma unroll
    for (int ks = 0; ks < 4; ++ks) {
        f16x8 a[4];
#pragma unroll
        for (int m = 0; m < 4; ++m)
            a[m] = *(const f16x8*)(lds + (m * 16 + r16) * (AP * 2) + ks * 64 + g16 * 16);
#pragma unroll
        for (int m = 0; m < 4; ++m)
#pragma unroll
            for (int n = 0; n < 2; ++n)
                acc[m][n] = __builtin_amdgcn_mfma_f32_16x16x32_f16(a[m], bw[ks][n], acc[m][n], 0, 0, 0);
    }
    float bias0 = ball[384 + cb + r16];
    float bias1 = ball[384 + cb + 16 + r16];

    __syncthreads();                              // all waves done reading A-tile
    float* e_lds = (float*)lds;                   // reuse as f32 E tile [64][EP]
#pragma unroll
    for (int m = 0; m < 4; ++m)
#pragma unroll
        for (int r = 0; r < 4; ++r) {
            int row = m * 16 + g16 * 4 + r;
            e_lds[row * EP + cb + r16]      = acc[m][0][r] + bias0;
            e_lds[row * EP + cb + 16 + r16] = acc[m][1][r] + bias1;
        }
    __syncthreads();

    // ---- epilogue: dot(E, K*Q)*scale, clamp, exp; f16 score at CSR slot ----
#pragma unroll
    for (int it = 0; it < 2; ++it) {
        int task = t + it * 256;
        int el = task >> 3, h = task & 7;
        int eg = e0 + el;
        if (eg < NE) {
            const f16x8* Kp = (const f16x8*)(Kb + (size_t)sArr[it] * 128 + h * 16);
            const f16x8* Qp = (const f16x8*)(Qb + (size_t)dArr[it] * 128 + h * 16);
            f16x8 k0 = Kp[0], k1 = Kp[1];
            f16x8 q0 = Qp[0], q1 = Qp[1];
            float dot = 0.f;
#pragma unroll
            for (int jj = 0; jj < 2; ++jj) {
                f32x4 ev0 = *(const f32x4*)(e_lds + el * EP + h * 16 + jj * 8);
                f32x4 ev1 = *(const f32x4*)(e_lds + el * EP + h * 16 + jj * 8 + 4);
                const f16x8& kk = jj == 0 ? k0 : k1;
                const f16x8& qq = jj == 0 ? q0 : q1;
#pragma unroll
                for (int r = 0; r < 4; ++r) {
                    dot += ev0[r] * (float)kk[r] * (float)qq[r];
                    dot += ev1[r] * (float)kk[r + 4] * (float)qq[r + 4];
                }
            }
            float sv = fminf(fmaxf(dot * 0.25f, -5.0f), 5.0f);
            int slot = slotArr[el];               // per-edge 8xf16 = contiguous 16B
            scores[(size_t)slot * 8 + h] = (_Float16)__expf(sv);
        }
    }
}

// ---------------- K5: gather/aggregate ----------------
// 16 threads per node (f16x8 = 16B V loads), 16 nodes per block, 4-deep unroll.
// ebuf + scores reads SEQUENTIAL (CSR order); only V rows random.
__global__ __launch_bounds__(256) void gather_kernel(
        const int* __restrict__ offsets, const int* __restrict__ ebuf,
        const _Float16* __restrict__ scores, const _Float16* __restrict__ Vb,
        float* __restrict__ out, int N) {
    int node = blockIdx.x * 16 + (threadIdx.x >> 4);
    int c8 = threadIdx.x & 15;                    // 8-col slot: cols [c8*8, c8*8+8)
    if (node >= N) return;
    int h = c8 >> 1;                              // head for these 8 cols
    int beg = offsets[node], end = offsets[node + 1];
    float a0[8], a1[8];
#pragma unroll
    for (int k = 0; k < 8; ++k) { a0[k] = 0.f; a1[k] = 0.f; }
    int j = beg;
    for (; j + 4 <= end; j += 4) {
        int s0 = ebuf[j], s1 = ebuf[j + 1], s2 = ebuf[j + 2], s3 = ebuf[j + 3];
        f16x8 v0 = *(const f16x8*)(Vb + s0 + c8 * 8);
        f16x8 v1 = *(const f16x8*)(Vb + s1 + c8 * 8);
        f16x8 v2 = *(const f16x8*)(Vb + s2 + c8 * 8);
        f16x8 v3 = *(const f16x8*)(Vb + s3 + c8 * 8);
        float sc0 = (float)scores[(size_t)(j    ) * 8 + h];
        float sc1 = (float)scores[(size_t)(j + 1) * 8 + h];
        float sc2 = (float)scores[(size_t)(j + 2) * 8 + h];
        float sc3 = (float)scores[(size_t)(j + 3) * 8 + h];
#pragma unroll
        for (int k = 0; k < 8; ++k) {
            a0[k] += sc0 * (float)v0[k] + sc2 * (float)v2[k];
            a1[k] += sc1 * (float)v1[k] + sc3 * (float)v3[k];
        }
    }
    for (; j < end; ++j) {
        int s = ebuf[j];
        f16x8 v = *(const f16x8*)(Vb + s + c8 * 8);
        float sc = (float)scores[(size_t)j * 8 + h];
#pragma unroll
        for (int k = 0; k < 8; ++k) a0[k] += sc * (float)v[k];
    }
    f32x4 o0, o1;
#pragma unroll
    for (int k = 0; k < 4; ++k) { o0[k] = a0[k] + a1[k]; o1[k] = a0[k + 4] + a1[k + 4]; }
    float* op = out + (size_t)node * 128 + c8 * 8;
    *(f32x4*)op = o0;
    *(f32x4*)(op + 4) = o1;
}

// ---------------- launcher ----------------
extern "C" void kernel_launch(void* const* d_in, const int* in_sizes, int n_in,
                              void* d_out, int out_size, void* d_ws, size_t ws_size,
                              hipStream_t stream) {
    const float* x   = (const float*)d_in[0];
    const float* ea  = (const float*)d_in[1];
    const int* eidx  = (const int*)d_in[2];
    const float* Wq  = (const float*)d_in[4];  const float* bq = (const float*)d_in[5];
    const float* Wk  = (const float*)d_in[6];  const float* bk = (const float*)d_in[7];
    const float* We  = (const float*)d_in[8];  const float* be = (const float*)d_in[9];
    const float* Wv  = (const float*)d_in[10]; const float* bv = (const float*)d_in[11];
    const int N  = in_sizes[0] / 128;
    const int NE = in_sizes[2] / 2;
    const int* srcp = eidx;
    const int* dstp = eidx + NE;
    float* out = (float*)d_out;

    char* ws = (char*)d_ws;
    size_t o = 0;
    auto alloc = [&](size_t b) { size_t r = o; o += (b + 255) & ~(size_t)255; return r; };
    _Float16* Qb     = (_Float16*)(ws + alloc((size_t)N * 128 * 2));
    _Float16* Kb     = (_Float16*)(ws + alloc((size_t)N * 128 * 2));
    _Float16* Vb     = (_Float16*)(ws + alloc((size_t)N * 128 * 2));
    _Float16* scores = (_Float16*)(ws + alloc((size_t)NE * 8 * 2));
    _Float16* Wf     = (_Float16*)(ws + alloc(512 * 128 * 2));
    float* ball      = (float*)(ws + alloc(512 * 4));
    int* counts      = (int*)(ws + alloc((size_t)(N + 1) * 4));
    int* offsets     = (int*)(ws + alloc((size_t)(N + 1) * 4));
    int* cursors     = (int*)(ws + alloc((size_t)N * 4));
    int* ebuf        = (int*)(ws + alloc((size_t)NE * 4));
    int* partials    = (int*)(ws + alloc(64 * 4));
    (void)ws_size; (void)n_in; (void)out_size;

    (void)hipMemsetAsync(counts, 0, (size_t)(N + 1) * 4, stream);

    convert_weights<<<256, 256, 0, stream>>>(Wq, bq, Wk, bk, We, be, Wv, bv,
                                             dstp, NE, Wf, ball, counts);

    int nb = (N + 1023) / 1024;
    scan1_kernel<<<nb, 1024, 0, stream>>>(counts, offsets, partials, N);
    scanB_kernel<<<nb, 1024, 0, stream>>>(counts, offsets, cursors, partials, N, NE);

    qkv_kernel<<<(N + 63) / 64, 256, 0, stream>>>(x, Wf, ball, Qb, Kb, Vb, N);

    edge_kernel<<<(NE + 63) / 64, 256, 0, stream>>>(ea, srcp, dstp, Wf, ball,
                                                    Qb, Kb, scores, cursors, ebuf, NE);

    gather_kernel<<<(N + 15) / 16, 256, 0, stream>>>(offsets, ebuf, scores, Vb, out, N);
}